// Round 2
// baseline (216.891 us; speedup 1.0000x reference)
//
#include <hip/hip_runtime.h>

typedef __bf16 bf16_t;
typedef __bf16 bf16x8 __attribute__((ext_vector_type(8)));
typedef float floatx4 __attribute__((ext_vector_type(4)));

static constexpr int NN  = 8192;     // nodes
static constexpr int FIN = 512;
static constexpr int NH1 = 256;
static constexpr int NH2 = 128;
static constexpr int NE  = 262144;

// output layout (floats): h1, adj_rec, mu, logvar, z
static constexpr size_t OFF_H1     = 0;
static constexpr size_t OFF_ADJ    = (size_t)NN * NH1;          // 2097152
static constexpr size_t OFF_MU     = OFF_ADJ + (size_t)NN * NN; // 69206016
static constexpr size_t OFF_LOGVAR = OFF_MU + (size_t)NN * NH2; // 70254592
static constexpr size_t OFF_Z      = OFF_LOGVAR + (size_t)NN * NH2;

// ---------------- weight prep: transpose + convert to bf16 ----------------
// W1T[n][k] = W1[k][n]  (256x512) ; W23T[n][k] = n<128 ? W2[k][n] : W3[k][n-128] (256x256)
__global__ __launch_bounds__(256) void prep_weights(
    const float* __restrict__ W1, const float* __restrict__ W2,
    const float* __restrict__ W3, bf16_t* __restrict__ W1T,
    bf16_t* __restrict__ W23T) {
  const int i = blockIdx.x * 256 + threadIdx.x;
  if (i < NH1 * FIN) {
    const int n = i >> 9, k = i & 511;
    W1T[i] = (bf16_t)W1[k * NH1 + n];
  }
  if (i < NH1 * NH1) {
    const int n = i >> 8, k = i & 255;
    W23T[i] = (bf16_t)(n < NH2 ? W2[k * NH2 + n] : W3[k * NH2 + (n - NH2)]);
  }
}

// ---------------- CSR build ----------------
__global__ __launch_bounds__(256) void edge_count(const int* __restrict__ row,
                                                  int* __restrict__ counts) {
  const int e = blockIdx.x * 256 + threadIdx.x;
  if (e < NE) atomicAdd(&counts[row[e]], 1);
}

__global__ __launch_bounds__(1024) void scan8k(const int* __restrict__ counts,
                                               int* __restrict__ row_ptr) {
  __shared__ int part[1024];
  const int t = threadIdx.x;
  int v[8];
  int run = 0;
#pragma unroll
  for (int j = 0; j < 8; ++j) { run += counts[t * 8 + j]; v[j] = run; }
  part[t] = run;
  __syncthreads();
  for (int off = 1; off < 1024; off <<= 1) {
    const int x = (t >= off) ? part[t - off] : 0;
    __syncthreads();
    part[t] += x;
    __syncthreads();
  }
  const int base = (t > 0) ? part[t - 1] : 0;
#pragma unroll
  for (int j = 0; j < 8; ++j) row_ptr[t * 8 + j + 1] = base + v[j];
  if (t == 0) row_ptr[0] = 0;
}

__global__ __launch_bounds__(256) void edge_fill(const int* __restrict__ row,
                                                 const int* __restrict__ row_ptr,
                                                 int* __restrict__ cursor,
                                                 int* __restrict__ edge_idx) {
  const int e = blockIdx.x * 256 + threadIdx.x;
  if (e < NE) {
    const int r = row[e];
    const int p = atomicAdd(&cursor[r], 1);
    edge_idx[row_ptr[r] + p] = e;
  }
}

// ---------------- MFMA GEMM (bf16 inputs, f32 accumulate) ----------------
// C[M x Nc] = A[M x KD] * B[KD x Nc], with B provided transposed: BT[n][k].
// Block tile 128x128, 4 waves (2x2), each wave 64x64 = 4x4 frags of 16x16x32.
// Robust-k loading: A and B frags use the identical lane->k map, so result is
// exact for any HW k-order; only C/D layout (HW-verified) is relied upon.
template <int KD, bool ABF, int EPI>
__global__ __launch_bounds__(256) void mfma_gemm(
    const float* __restrict__ Af, const bf16_t* __restrict__ Abf,
    const bf16_t* __restrict__ BT, float* __restrict__ C, int ldc,
    float* __restrict__ dout, bf16_t* __restrict__ zbf) {
  const int lane = threadIdx.x & 63;
  const int wid  = threadIdx.x >> 6;
  const int l15  = lane & 15;
  const int lg   = lane >> 4;
  const int brow = blockIdx.y * 128 + (wid >> 1) * 64;
  const int bcol = blockIdx.x * 128 + (wid & 1) * 64;

  floatx4 acc[4][4];
#pragma unroll
  for (int i = 0; i < 4; ++i)
#pragma unroll
    for (int j = 0; j < 4; ++j) acc[i][j] = (floatx4){0.f, 0.f, 0.f, 0.f};

#pragma unroll 1
  for (int kk = 0; kk < KD; kk += 32) {
    bf16x8 a[4], b[4];
#pragma unroll
    for (int rt = 0; rt < 4; ++rt) {
      const int r = brow + rt * 16 + l15;
      if constexpr (ABF) {
        a[rt] = *(const bf16x8*)(Abf + (size_t)r * KD + kk + lg * 8);
      } else {
        const float* p = Af + (size_t)r * KD + kk + lg * 8;
        const floatx4 lo = *(const floatx4*)p;
        const floatx4 hi = *(const floatx4*)(p + 4);
        bf16x8 t;
        t[0] = (bf16_t)lo[0]; t[1] = (bf16_t)lo[1];
        t[2] = (bf16_t)lo[2]; t[3] = (bf16_t)lo[3];
        t[4] = (bf16_t)hi[0]; t[5] = (bf16_t)hi[1];
        t[6] = (bf16_t)hi[2]; t[7] = (bf16_t)hi[3];
        a[rt] = t;
      }
    }
#pragma unroll
    for (int ct = 0; ct < 4; ++ct) {
      const int c = bcol + ct * 16 + l15;
      b[ct] = *(const bf16x8*)(BT + (size_t)c * KD + kk + lg * 8);
    }
#pragma unroll
    for (int rt = 0; rt < 4; ++rt)
#pragma unroll
      for (int ct = 0; ct < 4; ++ct)
        acc[rt][ct] = __builtin_amdgcn_mfma_f32_16x16x32_bf16(
            a[rt], b[ct], acc[rt][ct], 0, 0, 0);
  }

#pragma unroll
  for (int rt = 0; rt < 4; ++rt) {
#pragma unroll
    for (int ct = 0; ct < 4; ++ct) {
#pragma unroll
      for (int r = 0; r < 4; ++r) {
        const int orow = brow + rt * 16 + lg * 4 + r;
        const int ocol = bcol + ct * 16 + l15;
        const float v = acc[rt][ct][r];
        if constexpr (EPI == 0) {
          C[(size_t)orow * ldc + ocol] = v;
        } else {
          if (ocol < NH2) {
            dout[OFF_MU + (size_t)orow * NH2 + ocol] = v;
            dout[OFF_Z + (size_t)orow * NH2 + ocol] = v;
            zbf[orow * NH2 + ocol] = (bf16_t)v;
          } else {
            dout[OFF_LOGVAR + (size_t)orow * NH2 + (ocol - NH2)] = v;
          }
        }
      }
    }
  }
}

// ---------------- SPMM: one wave per row, d=256 ----------------
template <bool RELU>
__global__ __launch_bounds__(256) void spmm256(
    const int* __restrict__ row_ptr, const int* __restrict__ edge_idx,
    const int* __restrict__ col, const float* __restrict__ edge_w,
    const float* __restrict__ src, float* __restrict__ dst) {
  const int lane = threadIdx.x & 63;
  const int r = blockIdx.x * 4 + (threadIdx.x >> 6);
  const int beg = row_ptr[r];
  const int end = row_ptr[r + 1];
  floatx4 acc = (floatx4){0.f, 0.f, 0.f, 0.f};
  for (int base = beg; base < end; base += 64) {
    const int t = base + lane;
    const bool valid = t < end;
    const int ei = valid ? edge_idx[t] : 0;
    const int c = valid ? col[ei] : 0;
    const float w = valid ? edge_w[ei] : 0.f;
    const int cnt = min(64, end - base);
    for (int j = 0; j < cnt; ++j) {
      const int cj = __shfl(c, j);
      const float wj = __shfl(w, j);
      const floatx4 v = *(const floatx4*)(src + (size_t)cj * NH1 + lane * 4);
#pragma unroll
      for (int q = 0; q < 4; ++q) acc[q] += wj * v[q];
    }
  }
  if constexpr (RELU) {
#pragma unroll
    for (int q = 0; q < 4; ++q) acc[q] = fmaxf(acc[q], 0.f);
  }
  *(floatx4*)(dst + (size_t)r * NH1 + lane * 4) = acc;
}

extern "C" void kernel_launch(void* const* d_in, const int* in_sizes, int n_in,
                              void* d_out, int out_size, void* d_ws, size_t ws_size,
                              hipStream_t stream) {
  const float* x      = (const float*)d_in[0];
  const float* W1     = (const float*)d_in[1];
  const float* W2     = (const float*)d_in[2];
  const float* W3     = (const float*)d_in[3];
  const float* edge_w = (const float*)d_in[4];
  const int*   row    = (const int*)d_in[5];
  const int*   col    = (const int*)d_in[6];
  float* out = (float*)d_out;
  char*  ws  = (char*)d_ws;

  // workspace layout (bytes)
  float*  XW   = (float*)(ws);                         // 8 MB
  float*  g    = (float*)(ws + (8u << 20));            // 8 MB
  bf16_t* zbf  = (bf16_t*)(ws + (16u << 20));          // 2 MB
  bf16_t* W1T  = (bf16_t*)(ws + (18u << 20));          // 256 KB
  bf16_t* W23T = (bf16_t*)(ws + (18u << 20) + (1u << 19)); // 128 KB
  int* counts   = (int*)(ws + (19u << 20));
  int* cursor   = counts + NN;
  int* row_ptr  = cursor + NN;        // NN+1 ints
  int* edge_idx = row_ptr + NN + 8;   // NE ints

  hipMemsetAsync(counts, 0, 2 * NN * sizeof(int), stream);
  prep_weights<<<512, 256, 0, stream>>>(W1, W2, W3, W1T, W23T);
  edge_count<<<NE / 256, 256, 0, stream>>>(row, counts);
  scan8k<<<1, 1024, 0, stream>>>(counts, row_ptr);
  edge_fill<<<NE / 256, 256, 0, stream>>>(row, row_ptr, cursor, edge_idx);

  // XW = x @ W1   [8192 x 256]
  mfma_gemm<FIN, false, 0><<<dim3(NH1 / 128, NN / 128), 256, 0, stream>>>(
      x, nullptr, W1T, XW, NH1, nullptr, nullptr);
  // h1 = relu(A . XW)  -> out
  spmm256<true><<<NN / 4, 256, 0, stream>>>(row_ptr, edge_idx, col, edge_w, XW,
                                            out + OFF_H1);
  // g = A . h1
  spmm256<false><<<NN / 4, 256, 0, stream>>>(row_ptr, edge_idx, col, edge_w,
                                             out + OFF_H1, g);
  // [mu | logvar] = g @ [W2 | W3]; also writes z and zbf
  mfma_gemm<NH1, false, 1><<<dim3(NH1 / 128, NN / 128), 256, 0, stream>>>(
      g, nullptr, W23T, nullptr, 0, out, zbf);
  // adj_rec = z @ z^T  [8192 x 8192]
  mfma_gemm<NH2, true, 0><<<dim3(NN / 128, NN / 128), 256, 0, stream>>>(
      nullptr, zbf, zbf, out + OFF_ADJ, NN, nullptr, nullptr);
}

// Round 3
// 194.936 us; speedup vs baseline: 1.1126x; 1.1126x over previous
//
#include <hip/hip_runtime.h>

typedef __bf16 bf16_t;
typedef __bf16 bf16x4 __attribute__((ext_vector_type(4)));
typedef __bf16 bf16x8 __attribute__((ext_vector_type(8)));
typedef float floatx4 __attribute__((ext_vector_type(4)));

static constexpr int NN  = 8192;
static constexpr int FIN = 512;
static constexpr int NH1 = 256;
static constexpr int NH2 = 128;
static constexpr int NE  = 262144;

// output layout (floats): h1, adj_rec, mu, logvar, z
static constexpr size_t OFF_H1     = 0;
static constexpr size_t OFF_ADJ    = (size_t)NN * NH1;
static constexpr size_t OFF_MU     = OFF_ADJ + (size_t)NN * NN;
static constexpr size_t OFF_LOGVAR = OFF_MU + (size_t)NN * NH2;
static constexpr size_t OFF_Z      = OFF_LOGVAR + (size_t)NN * NH2;

// ---------------- fused prep: weight transpose/convert + edge count ----------------
__global__ __launch_bounds__(256) void prep_all(
    const float* __restrict__ W1, const float* __restrict__ W2,
    const float* __restrict__ W3, const int* __restrict__ row,
    bf16_t* __restrict__ W1T, bf16_t* __restrict__ W23T,
    int* __restrict__ counts) {
  const int gid = blockIdx.x * 256 + threadIdx.x;  // grid = 1024*256 == NE exactly
  atomicAdd(&counts[row[gid]], 1);
  if (gid < NH1 * FIN) {
    const int n = gid >> 9, k = gid & 511;
    W1T[gid] = (bf16_t)W1[k * NH1 + n];
  }
  if (gid < NH1 * NH1) {
    const int n = gid >> 8, k = gid & 255;
    W23T[gid] = (bf16_t)(n < NH2 ? W2[k * NH2 + n] : W3[k * NH2 + (n - NH2)]);
  }
}

// ---------------- scan of 8192 counts -> row_ptr ----------------
__global__ __launch_bounds__(1024) void scan8k(const int* __restrict__ counts,
                                               int* __restrict__ row_ptr) {
  __shared__ int part[1024];
  const int t = threadIdx.x;
  int v[8];
  int run = 0;
#pragma unroll
  for (int j = 0; j < 8; ++j) { run += counts[t * 8 + j]; v[j] = run; }
  part[t] = run;
  __syncthreads();
  for (int off = 1; off < 1024; off <<= 1) {
    const int x = (t >= off) ? part[t - off] : 0;
    __syncthreads();
    part[t] += x;
    __syncthreads();
  }
  const int base = (t > 0) ? part[t - 1] : 0;
#pragma unroll
  for (int j = 0; j < 8; ++j) row_ptr[t * 8 + j + 1] = base + v[j];
  if (t == 0) row_ptr[0] = 0;
}

// ---------------- edge fill: scatter packed (col, weight) ----------------
__global__ __launch_bounds__(256) void edge_fill(
    const int* __restrict__ row, const int* __restrict__ col,
    const float* __restrict__ edge_w, const int* __restrict__ row_ptr,
    int* __restrict__ cursor, uint2* __restrict__ pw) {
  const int e = blockIdx.x * 256 + threadIdx.x;
  const int r = row[e];
  const int p = atomicAdd(&cursor[r], 1);
  uint2 v;
  v.x = (unsigned)col[e];
  v.y = __float_as_uint(edge_w[e]);
  pw[row_ptr[r] + p] = v;
}

// ---------------- MFMA GEMM (bf16 inputs, f32 accumulate) ----------------
// C[M x Nc] = A[M x KD] * BT[Nc x KD]^T. Block 128x128, 4 waves 2x2, wave 64x64.
// A and B frags use the identical lane->k map -> exact for any HW k-order.
// EPI: 0 = f32 C (nontemporal)   1 = mu/z/logvar f32 (nt) + zbf bf16   2 = bf16 only
template <int KD, bool ABF, int EPI, bool SWZ>
__global__ __launch_bounds__(256) void mfma_gemm(
    const float* __restrict__ Af, const bf16_t* __restrict__ Abf,
    const bf16_t* __restrict__ BT, float* __restrict__ C, int ldc,
    float* __restrict__ dout, bf16_t* __restrict__ zbf, int ldz) {
  int bx, by;
  if constexpr (SWZ) {  // 4096 blocks, 64x64 tiles: XCD gets 8 contiguous row-panels
    const int bid = blockIdx.x;
    const int s = (bid & 7) * 512 + (bid >> 3);
    by = s >> 6; bx = s & 63;
  } else {
    bx = blockIdx.x; by = blockIdx.y;
  }
  const int lane = threadIdx.x & 63;
  const int wid  = threadIdx.x >> 6;
  const int l15  = lane & 15;
  const int lg   = lane >> 4;
  const int brow = by * 128 + (wid >> 1) * 64;
  const int bcol = bx * 128 + (wid & 1) * 64;

  floatx4 acc[4][4];
#pragma unroll
  for (int i = 0; i < 4; ++i)
#pragma unroll
    for (int j = 0; j < 4; ++j) acc[i][j] = (floatx4){0.f, 0.f, 0.f, 0.f};

#pragma unroll 1
  for (int kk = 0; kk < KD; kk += 32) {
    bf16x8 a[4], b[4];
#pragma unroll
    for (int rt = 0; rt < 4; ++rt) {
      const int r = brow + rt * 16 + l15;
      if constexpr (ABF) {
        a[rt] = *(const bf16x8*)(Abf + (size_t)r * KD + kk + lg * 8);
      } else {
        const float* p = Af + (size_t)r * KD + kk + lg * 8;
        const floatx4 lo = *(const floatx4*)p;
        const floatx4 hi = *(const floatx4*)(p + 4);
        bf16x8 t;
        t[0] = (bf16_t)lo[0]; t[1] = (bf16_t)lo[1];
        t[2] = (bf16_t)lo[2]; t[3] = (bf16_t)lo[3];
        t[4] = (bf16_t)hi[0]; t[5] = (bf16_t)hi[1];
        t[6] = (bf16_t)hi[2]; t[7] = (bf16_t)hi[3];
        a[rt] = t;
      }
    }
#pragma unroll
    for (int ct = 0; ct < 4; ++ct) {
      const int c = bcol + ct * 16 + l15;
      b[ct] = *(const bf16x8*)(BT + (size_t)c * KD + kk + lg * 8);
    }
#pragma unroll
    for (int rt = 0; rt < 4; ++rt)
#pragma unroll
      for (int ct = 0; ct < 4; ++ct)
        acc[rt][ct] = __builtin_amdgcn_mfma_f32_16x16x32_bf16(
            a[rt], b[ct], acc[rt][ct], 0, 0, 0);
  }

#pragma unroll
  for (int rt = 0; rt < 4; ++rt) {
#pragma unroll
    for (int ct = 0; ct < 4; ++ct) {
#pragma unroll
      for (int r = 0; r < 4; ++r) {
        const int orow = brow + rt * 16 + lg * 4 + r;
        const int ocol = bcol + ct * 16 + l15;
        const float v = acc[rt][ct][r];
        if constexpr (EPI == 0) {
          __builtin_nontemporal_store(v, &C[(size_t)orow * ldc + ocol]);
        } else if constexpr (EPI == 1) {
          if (ocol < NH2) {
            __builtin_nontemporal_store(v, &dout[OFF_MU + (size_t)orow * NH2 + ocol]);
            __builtin_nontemporal_store(v, &dout[OFF_Z + (size_t)orow * NH2 + ocol]);
            zbf[orow * ldz + ocol] = (bf16_t)v;
          } else {
            __builtin_nontemporal_store(
                v, &dout[OFF_LOGVAR + (size_t)orow * NH2 + (ocol - NH2)]);
          }
        } else {
          zbf[orow * ldz + ocol] = (bf16_t)v;
        }
      }
    }
  }
}

// ---------------- SPMM over bf16 features, d=256: one wave per row ----------------
template <bool RELU>
__global__ __launch_bounds__(256) void spmm_b(
    const int* __restrict__ row_ptr, const uint2* __restrict__ pw,
    const bf16_t* __restrict__ src, float* __restrict__ dst_f,
    bf16_t* __restrict__ dst_b) {
  const int lane = threadIdx.x & 63;
  const int r = blockIdx.x * 4 + (threadIdx.x >> 6);
  const int beg = row_ptr[r];
  const int end = row_ptr[r + 1];
  float a0 = 0.f, a1 = 0.f, a2 = 0.f, a3 = 0.f;
  for (int base = beg; base < end; base += 64) {
    const int t = base + lane;
    uint2 cw;
    cw.x = 0; cw.y = 0;
    if (t < end) cw = pw[t];
    const int cnt = min(64, end - base);
    for (int j = 0; j < cnt; ++j) {
      const int cj = __shfl((int)cw.x, j);
      const float wj = __shfl(__uint_as_float(cw.y), j);
      const bf16x4 v = *(const bf16x4*)(src + (size_t)cj * NH1 + lane * 4);
      a0 += wj * (float)v[0];
      a1 += wj * (float)v[1];
      a2 += wj * (float)v[2];
      a3 += wj * (float)v[3];
    }
  }
  if constexpr (RELU) {
    a0 = fmaxf(a0, 0.f); a1 = fmaxf(a1, 0.f);
    a2 = fmaxf(a2, 0.f); a3 = fmaxf(a3, 0.f);
  }
  if (dst_f) {
    floatx4 o = (floatx4){a0, a1, a2, a3};
    *(floatx4*)(dst_f + (size_t)r * NH1 + lane * 4) = o;
  }
  if (dst_b) {
    bf16x4 o;
    o[0] = (bf16_t)a0; o[1] = (bf16_t)a1; o[2] = (bf16_t)a2; o[3] = (bf16_t)a3;
    *(bf16x4*)(dst_b + (size_t)r * NH1 + lane * 4) = o;
  }
}

extern "C" void kernel_launch(void* const* d_in, const int* in_sizes, int n_in,
                              void* d_out, int out_size, void* d_ws, size_t ws_size,
                              hipStream_t stream) {
  const float* x      = (const float*)d_in[0];
  const float* W1     = (const float*)d_in[1];
  const float* W2     = (const float*)d_in[2];
  const float* W3     = (const float*)d_in[3];
  const float* edge_w = (const float*)d_in[4];
  const int*   row    = (const int*)d_in[5];
  const int*   col    = (const int*)d_in[6];
  float* out = (float*)d_out;
  char*  ws  = (char*)d_ws;

  // workspace layout (bytes); total ~16.6 MB
  bf16_t* XWb  = (bf16_t*)(ws);                         // 4 MB  [8192][256]
  bf16_t* h1b  = (bf16_t*)(ws + (4u << 20));            // 4 MB
  bf16_t* gb   = (bf16_t*)(ws + (8u << 20));            // 4 MB
  bf16_t* zbf  = (bf16_t*)(ws + (12u << 20));           // 2 MB  [8192][128]
  bf16_t* W1T  = (bf16_t*)(ws + (14u << 20));           // 256 KB
  bf16_t* W23T = (bf16_t*)(ws + (14u << 20) + (1u << 19));
  int* counts   = (int*)(ws + (15u << 20));
  int* cursor   = counts + NN;
  int* row_ptr  = cursor + NN;       // NN+1
  uint2* pw     = (uint2*)(ws + (15u << 20) + (1u << 18));  // 2 MB

  hipMemsetAsync(counts, 0, 2 * NN * sizeof(int), stream);
  prep_all<<<NE / 256, 256, 0, stream>>>(W1, W2, W3, row, W1T, W23T, counts);
  scan8k<<<1, 1024, 0, stream>>>(counts, row_ptr);
  edge_fill<<<NE / 256, 256, 0, stream>>>(row, col, edge_w, row_ptr, cursor, pw);

  // XWb = bf16(x @ W1)   [8192 x 256]
  mfma_gemm<FIN, false, 2, false><<<dim3(NH1 / 128, NN / 128), 256, 0, stream>>>(
      x, nullptr, W1T, nullptr, 0, nullptr, XWb, NH1);
  // h1 = relu(A . XWb) -> out (f32) + h1b (bf16)
  spmm_b<true><<<NN / 4, 256, 0, stream>>>(row_ptr, pw, XWb, out + OFF_H1, h1b);
  // gb = bf16(A . h1b)
  spmm_b<false><<<NN / 4, 256, 0, stream>>>(row_ptr, pw, h1b, nullptr, gb);
  // [mu | logvar] = gb @ [W2 | W3]; writes mu/z/logvar f32 + zbf bf16
  mfma_gemm<NH1, true, 1, false><<<dim3(NH1 / 128, NN / 128), 256, 0, stream>>>(
      nullptr, gb, W23T, nullptr, 0, out, zbf, NH2);
  // adj_rec = z @ z^T  [8192 x 8192], XCD-swizzled, nontemporal stores
  mfma_gemm<NH2, true, 0, true><<<4096, 256, 0, stream>>>(
      nullptr, zbf, zbf, out + OFF_ADJ, NN, nullptr, nullptr, 0);
}

// Round 4
// 172.952 us; speedup vs baseline: 1.2541x; 1.1271x over previous
//
#include <hip/hip_runtime.h>

typedef __bf16 bf16_t;
typedef __bf16 bf16x4 __attribute__((ext_vector_type(4)));
typedef __bf16 bf16x8 __attribute__((ext_vector_type(8)));
typedef float floatx4 __attribute__((ext_vector_type(4)));

static constexpr int NN  = 8192;
static constexpr int FIN = 512;
static constexpr int NH1 = 256;
static constexpr int NH2 = 128;
static constexpr int NE  = 262144;

// output layout (floats): h1, adj_rec, mu, logvar, z
static constexpr size_t OFF_H1     = 0;
static constexpr size_t OFF_ADJ    = (size_t)NN * NH1;
static constexpr size_t OFF_MU     = OFF_ADJ + (size_t)NN * NN;
static constexpr size_t OFF_LOGVAR = OFF_MU + (size_t)NN * NH2;
static constexpr size_t OFF_Z      = OFF_LOGVAR + (size_t)NN * NH2;

// ---------------- fused prep: weight transpose/convert + edge count ----------------
__global__ __launch_bounds__(256) void prep_all(
    const float* __restrict__ W1, const float* __restrict__ W2,
    const float* __restrict__ W3, const int* __restrict__ row,
    bf16_t* __restrict__ W1T, bf16_t* __restrict__ W23T,
    int* __restrict__ counts) {
  const int gid = blockIdx.x * 256 + threadIdx.x;  // grid*256 == NE exactly
  atomicAdd(&counts[row[gid]], 1);
  if (gid < NH1 * FIN) {
    const int n = gid >> 9, k = gid & 511;
    W1T[gid] = (bf16_t)W1[k * NH1 + n];
  }
  if (gid < NH1 * NH1) {
    const int n = gid >> 8, k = gid & 255;
    W23T[gid] = (bf16_t)(n < NH2 ? W2[k * NH2 + n] : W3[k * NH2 + (n - NH2)]);
  }
}

// ---------------- scan of 8192 counts -> row_ptr ----------------
__global__ __launch_bounds__(1024) void scan8k(const int* __restrict__ counts,
                                               int* __restrict__ row_ptr) {
  __shared__ int part[1024];
  const int t = threadIdx.x;
  int v[8];
  int run = 0;
#pragma unroll
  for (int j = 0; j < 8; ++j) { run += counts[t * 8 + j]; v[j] = run; }
  part[t] = run;
  __syncthreads();
  for (int off = 1; off < 1024; off <<= 1) {
    const int x = (t >= off) ? part[t - off] : 0;
    __syncthreads();
    part[t] += x;
    __syncthreads();
  }
  const int base = (t > 0) ? part[t - 1] : 0;
#pragma unroll
  for (int j = 0; j < 8; ++j) row_ptr[t * 8 + j + 1] = base + v[j];
  if (t == 0) row_ptr[0] = 0;
}

// ---------------- edge fill: scatter packed (col, weight) ----------------
__global__ __launch_bounds__(256) void edge_fill(
    const int* __restrict__ row, const int* __restrict__ col,
    const float* __restrict__ edge_w, const int* __restrict__ row_ptr,
    int* __restrict__ cursor, uint2* __restrict__ pw) {
  const int e = blockIdx.x * 256 + threadIdx.x;
  const int r = row[e];
  const int p = atomicAdd(&cursor[r], 1);
  uint2 v;
  v.x = (unsigned)col[e];
  v.y = __float_as_uint(edge_w[e]);
  pw[row_ptr[r] + p] = v;
}

// ---------------- MFMA GEMM (bf16 inputs, f32 accumulate) ----------------
// Block tile (RT*32) x 128, 4 waves 2x2, wave tile (RT*16) x 64.
// A/B frags share the same lane->k map -> exact for any HW k-order.
// EPI: 0 = f32 C via LDS-transposed float4 nt stores (adj)
//      1 = mu/z/logvar f32 + zbf bf16     2 = bf16 only
template <int KD, int RT, bool ABF, int EPI, bool SWZ>
__global__ __launch_bounds__(256) void mfma_gemm(
    const float* __restrict__ Af, const bf16_t* __restrict__ Abf,
    const bf16_t* __restrict__ BT, float* __restrict__ C, int ldc,
    float* __restrict__ dout, bf16_t* __restrict__ zbf, int ldz) {
  int bx, by;
  if constexpr (SWZ) {  // 4096 blocks over 64x64 tile grid: XCD-contiguous panels
    const int bid = blockIdx.x;
    const int s = (bid & 7) * 512 + (bid >> 3);
    by = s >> 6; bx = s & 63;
  } else {
    bx = blockIdx.x; by = blockIdx.y;
  }
  const int lane = threadIdx.x & 63;
  const int wid  = threadIdx.x >> 6;
  const int l15  = lane & 15;
  const int lg   = lane >> 4;
  const int brow = by * (RT * 32) + (wid >> 1) * (RT * 16);
  const int bcol = bx * 128 + (wid & 1) * 64;

  floatx4 acc[RT][4];
#pragma unroll
  for (int i = 0; i < RT; ++i)
#pragma unroll
    for (int j = 0; j < 4; ++j) acc[i][j] = (floatx4){0.f, 0.f, 0.f, 0.f};

#pragma unroll 1
  for (int kk = 0; kk < KD; kk += 32) {
    bf16x8 a[RT], b[4];
#pragma unroll
    for (int rt = 0; rt < RT; ++rt) {
      const int r = brow + rt * 16 + l15;
      if constexpr (ABF) {
        a[rt] = *(const bf16x8*)(Abf + (size_t)r * KD + kk + lg * 8);
      } else {
        const float* p = Af + (size_t)r * KD + kk + lg * 8;
        const floatx4 lo = *(const floatx4*)p;
        const floatx4 hi = *(const floatx4*)(p + 4);
        bf16x8 t;
        t[0] = (bf16_t)lo[0]; t[1] = (bf16_t)lo[1];
        t[2] = (bf16_t)lo[2]; t[3] = (bf16_t)lo[3];
        t[4] = (bf16_t)hi[0]; t[5] = (bf16_t)hi[1];
        t[6] = (bf16_t)hi[2]; t[7] = (bf16_t)hi[3];
        a[rt] = t;
      }
    }
#pragma unroll
    for (int ct = 0; ct < 4; ++ct) {
      const int c = bcol + ct * 16 + l15;
      b[ct] = *(const bf16x8*)(BT + (size_t)c * KD + kk + lg * 8);
    }
#pragma unroll
    for (int rt = 0; rt < RT; ++rt)
#pragma unroll
      for (int ct = 0; ct < 4; ++ct)
        acc[rt][ct] = __builtin_amdgcn_mfma_f32_16x16x32_bf16(
            a[rt], b[ct], acc[rt][ct], 0, 0, 0);
  }

  if constexpr (EPI == 0) {
    // LDS transpose -> float4 nontemporal stores (full-line coalesced)
    __shared__ float lt[4][64 * 68];
    float* L = lt[wid];
#pragma unroll
    for (int rt = 0; rt < RT; ++rt)
#pragma unroll
      for (int ct = 0; ct < 4; ++ct)
#pragma unroll
        for (int r = 0; r < 4; ++r)
          L[(rt * 16 + lg * 4 + r) * 68 + ct * 16 + l15] = acc[rt][ct][r];
    __syncthreads();
#pragma unroll
    for (int it = 0; it < 16; ++it) {
      const int idx = it * 64 + lane;
      const int rr = idx >> 4, c4 = idx & 15;
      const floatx4 v = *(const floatx4*)(L + rr * 68 + c4 * 4);
      __builtin_nontemporal_store(
          v, (floatx4*)(C + (size_t)(brow + rr) * ldc + bcol + c4 * 4));
    }
  } else {
#pragma unroll
    for (int rt = 0; rt < RT; ++rt) {
#pragma unroll
      for (int ct = 0; ct < 4; ++ct) {
#pragma unroll
        for (int r = 0; r < 4; ++r) {
          const int orow = brow + rt * 16 + lg * 4 + r;
          const int ocol = bcol + ct * 16 + l15;
          const float v = acc[rt][ct][r];
          if constexpr (EPI == 1) {
            if (ocol < NH2) {
              __builtin_nontemporal_store(v, &dout[OFF_MU + (size_t)orow * NH2 + ocol]);
              __builtin_nontemporal_store(v, &dout[OFF_Z + (size_t)orow * NH2 + ocol]);
              zbf[orow * ldz + ocol] = (bf16_t)v;
            } else {
              __builtin_nontemporal_store(
                  v, &dout[OFF_LOGVAR + (size_t)orow * NH2 + (ocol - NH2)]);
            }
          } else {
            zbf[orow * ldz + ocol] = (bf16_t)v;
          }
        }
      }
    }
  }
}

// ---------------- SPMM bf16, d=256: one wave per row, 4 edges in flight ----------------
template <bool RELU>
__global__ __launch_bounds__(256) void spmm_b(
    const int* __restrict__ row_ptr, const uint2* __restrict__ pw,
    const bf16_t* __restrict__ src, float* __restrict__ dst_f,
    bf16_t* __restrict__ dst_b) {
  const int lane = threadIdx.x & 63;
  const int r = blockIdx.x * 4 + (threadIdx.x >> 6);
  const int li = lane & 15;  // channel group: channels [li*16, li*16+16)
  const int g  = lane >> 4;  // edge slot 0..3
  const int beg = row_ptr[r];
  const int end = row_ptr[r + 1];
  float acc[16];
#pragma unroll
  for (int c = 0; c < 16; ++c) acc[c] = 0.f;

  for (int base = beg; base < end; base += 64) {
    const int t = base + lane;
    uint2 cw;
    cw.x = 0; cw.y = 0;
    if (t < end) cw = pw[t];
    const int cnt = min(64, end - base);
    for (int j4 = 0; j4 < cnt; j4 += 4) {
      const int slot = j4 + g;  // lanes with slot>=cnt picked up zeroed cw
      const int cj = __shfl((int)cw.x, slot);
      const float wj = __shfl(__uint_as_float(cw.y), slot);
      const bf16_t* p = src + (size_t)cj * NH1 + li * 16;
      const bf16x8 v0 = *(const bf16x8*)p;
      const bf16x8 v1 = *(const bf16x8*)(p + 8);
#pragma unroll
      for (int c = 0; c < 8; ++c) {
        acc[c]     += wj * (float)v0[c];
        acc[8 + c] += wj * (float)v1[c];
      }
    }
  }
  // reduce across the 4 edge-slot groups (lanes li, li+16, li+32, li+48)
#pragma unroll
  for (int c = 0; c < 16; ++c) {
    acc[c] += __shfl_xor(acc[c], 16);
    acc[c] += __shfl_xor(acc[c], 32);
    if constexpr (RELU) acc[c] = fmaxf(acc[c], 0.f);
  }
  // all lanes hold full sums; lane writes channels li*16 + g*4 .. +3
  const int ch = li * 16 + g * 4;
  if (dst_f) {
    floatx4 o = (floatx4){acc[g * 4], acc[g * 4 + 1], acc[g * 4 + 2], acc[g * 4 + 3]};
    *(floatx4*)(dst_f + (size_t)r * NH1 + ch) = o;
  }
  if (dst_b) {
    bf16x4 o;
    o[0] = (bf16_t)acc[g * 4];     o[1] = (bf16_t)acc[g * 4 + 1];
    o[2] = (bf16_t)acc[g * 4 + 2]; o[3] = (bf16_t)acc[g * 4 + 3];
    *(bf16x4*)(dst_b + (size_t)r * NH1 + ch) = o;
  }
}

extern "C" void kernel_launch(void* const* d_in, const int* in_sizes, int n_in,
                              void* d_out, int out_size, void* d_ws, size_t ws_size,
                              hipStream_t stream) {
  const float* x      = (const float*)d_in[0];
  const float* W1     = (const float*)d_in[1];
  const float* W2     = (const float*)d_in[2];
  const float* W3     = (const float*)d_in[3];
  const float* edge_w = (const float*)d_in[4];
  const int*   row    = (const int*)d_in[5];
  const int*   col    = (const int*)d_in[6];
  float* out = (float*)d_out;
  char*  ws  = (char*)d_ws;

  bf16_t* XWb  = (bf16_t*)(ws);                         // 4 MB  [8192][256]
  bf16_t* h1b  = (bf16_t*)(ws + (4u << 20));            // 4 MB
  bf16_t* gb   = (bf16_t*)(ws + (8u << 20));            // 4 MB
  bf16_t* zbf  = (bf16_t*)(ws + (12u << 20));           // 2 MB  [8192][128]
  bf16_t* W1T  = (bf16_t*)(ws + (14u << 20));           // 256 KB
  bf16_t* W23T = (bf16_t*)(ws + (14u << 20) + (1u << 19));
  int* counts   = (int*)(ws + (15u << 20));
  int* cursor   = counts + NN;
  int* row_ptr  = cursor + NN;       // NN+1
  uint2* pw     = (uint2*)(ws + (15u << 20) + (1u << 18));  // 2 MB

  hipMemsetAsync(counts, 0, 2 * NN * sizeof(int), stream);
  prep_all<<<NE / 256, 256, 0, stream>>>(W1, W2, W3, row, W1T, W23T, counts);
  scan8k<<<1, 1024, 0, stream>>>(counts, row_ptr);
  edge_fill<<<NE / 256, 256, 0, stream>>>(row, col, edge_w, row_ptr, cursor, pw);

  // XWb = bf16(x @ W1)   [8192 x 256], 64x128 block tiles -> 256 blocks
  mfma_gemm<FIN, 2, false, 2, false><<<dim3(NH1 / 128, NN / 64), 256, 0, stream>>>(
      x, nullptr, W1T, nullptr, 0, nullptr, XWb, NH1);
  // h1 = relu(A . XWb) -> out (f32) + h1b (bf16)
  spmm_b<true><<<NN / 4, 256, 0, stream>>>(row_ptr, pw, XWb, out + OFF_H1, h1b);
  // gb = bf16(A . h1b)
  spmm_b<false><<<NN / 4, 256, 0, stream>>>(row_ptr, pw, h1b, nullptr, gb);
  // [mu | logvar] = gb @ [W2 | W3]; writes mu/z/logvar f32 + zbf bf16
  mfma_gemm<NH1, 2, true, 1, false><<<dim3(NH1 / 128, NN / 64), 256, 0, stream>>>(
      nullptr, gb, W23T, nullptr, 0, out, zbf, NH2);
  // adj_rec = z @ z^T  [8192 x 8192], XCD-swizzled, LDS-transposed float4 nt stores
  mfma_gemm<NH2, 4, true, 0, true><<<4096, 256, 0, stream>>>(
      nullptr, zbf, zbf, out + OFF_ADJ, NN, nullptr, nullptr, 0);
}